// Round 10
// baseline (206.678 us; speedup 1.0000x reference)
//
#include <hip/hip_runtime.h>
#include <hip/hip_bf16.h>

#define NBATCH 4
#define NSEQ   1024
#define BNN    4096
#define CIN    128
#define COUT   256
#define RDIM   32
#define NEDGE  65536
#define NTILE  16      // 1024 / 64 t-tiles per row

// ---------- edge bucketing (counting sort by dst) ----------
__global__ void edge_hist(const int* __restrict__ ei_s, const int* __restrict__ ei_t,
                          int* __restrict__ cnt) {
    int gid = blockIdx.x * blockDim.x + threadIdx.x;   // 2*NEDGE
    int list = gid >> 16;
    int e = gid & (NEDGE - 1);
    const int* ei = list ? ei_t : ei_s;
    atomicAdd(&cnt[list * BNN + ei[NEDGE + e]], 1);
}

__global__ void edge_scan(const int* __restrict__ cnt, int* __restrict__ offs,
                          int* __restrict__ cursor) {
    __shared__ int sums[256];
    int list = blockIdx.x;
    int tid = threadIdx.x;
    int local[16];
    int s = 0;
#pragma unroll
    for (int k = 0; k < 16; k++) { local[k] = cnt[list * BNN + tid * 16 + k]; s += local[k]; }
    sums[tid] = s;
    __syncthreads();
    for (int off = 1; off < 256; off <<= 1) {
        int v = 0;
        if (tid >= off) v = sums[tid - off];
        __syncthreads();
        if (tid >= off) sums[tid] += v;
        __syncthreads();
    }
    int run = tid ? sums[tid - 1] : 0;
#pragma unroll
    for (int k = 0; k < 16; k++) {
        offs[list * (BNN + 1) + tid * 16 + k] = run;
        cursor[list * BNN + tid * 16 + k] = run;
        run += local[k];
    }
    if (tid == 255) offs[list * (BNN + 1) + BNN] = run;
}

__global__ void edge_place(const int* __restrict__ ei_s, const int* __restrict__ ei_t,
                           int* __restrict__ cursor, int* __restrict__ ssrc) {
    int gid = blockIdx.x * blockDim.x + threadIdx.x;   // 2*NEDGE
    int list = gid >> 16;
    int e = gid & (NEDGE - 1);
    const int* ei = list ? ei_t : ei_s;
    int dst = ei[NEDGE + e], src = ei[e];
    int p = atomicAdd(&cursor[list * BNN + dst], 1);
    ssrc[list * NEDGE + p] = src;
}

// t[n] = x[n] + sum_{e: dst=n} x[src_e] (128-wide). One block (128 thr) per node.
__global__ void gather_agg128(const float* __restrict__ x_s, const float* __restrict__ x_t,
                              const int* __restrict__ offs, const int* __restrict__ ssrc,
                              float* __restrict__ t_s, float* __restrict__ t_t) {
    __shared__ int sl[128];
    int node = blockIdx.x & (BNN - 1);
    int list = blockIdx.x >> 12;
    const float* x = list ? x_t : x_s;
    float* t = list ? t_t : t_s;
    int c = threadIdx.x;
    int beg = offs[list * (BNN + 1) + node], end = offs[list * (BNN + 1) + node + 1];
    float acc = x[(size_t)node * CIN + c];
    for (int base = beg; base < end; base += 128) {
        int cnt = min(128, end - base);
        __syncthreads();
        if (c < cnt) sl[c] = ssrc[list * NEDGE + base + c];
        __syncthreads();
        int e = 0;
        for (; e + 4 <= cnt; e += 4) {
            int n0 = sl[e], n1 = sl[e + 1], n2 = sl[e + 2], n3 = sl[e + 3];
            acc += x[(size_t)n0 * CIN + c] + x[(size_t)n1 * CIN + c]
                 + x[(size_t)n2 * CIN + c] + x[(size_t)n3 * CIN + c];
        }
        for (; e < cnt; e++) acc += x[(size_t)sl[e] * CIN + c];
    }
    t[(size_t)node * CIN + c] = acc;
}

// 32-wide gather; blockIdx.y selects (rs->trs, list-s) or (rt->trt, list-t).
__global__ void gather_agg32(const float* __restrict__ rs, const float* __restrict__ rtin,
                             const int* __restrict__ offs, const int* __restrict__ ssrc,
                             float* __restrict__ trs, float* __restrict__ trt) {
    int list = blockIdx.y;
    int node = blockIdx.x * 8 + (threadIdx.x >> 5);
    int c = threadIdx.x & 31;
    const float* in = list ? rtin : rs;
    float* outp = list ? trt : trs;
    int beg = offs[list * (BNN + 1) + node], end = offs[list * (BNN + 1) + node + 1];
    float acc = in[(size_t)node * RDIM + c];
    for (int e = beg; e < end; e++)
        acc += in[(size_t)ssrc[list * NEDGE + e] * RDIM + c];
    outp[(size_t)node * RDIM + c] = acc;
}

// h = relu(t @ W1 + b1), both graphs in one launch (grid 1024).
__global__ void psi1_gemm(const float* __restrict__ t_s, const float* __restrict__ t_t,
                          const float* __restrict__ W1, const float* __restrict__ b1,
                          float* __restrict__ h_s, float* __restrict__ h_t) {
    __shared__ float rows[8][CIN];
    int half = blockIdx.x >> 9;
    const float* t = half ? t_t : t_s;
    float* h = half ? h_t : h_s;
    int r0 = (blockIdx.x & 511) * 8;
    int tid = threadIdx.x;
    {
        int rr = tid >> 5, c4 = (tid & 31) << 2;
        *(float4*)&rows[rr][c4] = *(const float4*)(t + (size_t)(r0 + rr) * CIN + c4);
    }
    __syncthreads();
    float acc[8];
    float bias = b1[tid];
#pragma unroll
    for (int r = 0; r < 8; r++) acc[r] = bias;
    for (int k = 0; k < CIN; k++) {
        float w = W1[k * COUT + tid];
#pragma unroll
        for (int r = 0; r < 8; r++) acc[r] = fmaf(rows[r][k], w, acc[r]);
    }
#pragma unroll
    for (int r = 0; r < 8; r++)
        h[(size_t)(r0 + r) * COUT + tid] = fmaxf(acc[r], 0.f);
}

// S_hat[b] = h_s[b] @ h_t[b]^T. 64x64 tile, 4x4/thread, grid 1024 + XCD swizzle.
// Epilogue: per-(row, t-tile) partial softmax stats via width-16 shuffles.
__global__ __launch_bounds__(256) void shat_gemm(const float* __restrict__ hs,
                                                 const float* __restrict__ ht,
                                                 float* __restrict__ Sh,
                                                 float* __restrict__ pmax,
                                                 float* __restrict__ psum) {
    __shared__ float As[16][68];
    __shared__ float Bs[16][68];
    int flat = blockIdx.x;
    int swz = (flat & 7) * 128 + (flat >> 3);    // bijective: 1024 % 8 == 0
    int bx = swz & 15, by = (swz >> 4) & 15, bz = swz >> 8;
    int b  = bz;
    int s0 = by * 64, t0 = bx * 64;
    const float* A  = hs + (size_t)b * NSEQ * COUT;
    const float* Bm = ht + (size_t)b * NSEQ * COUT;
    int tid = threadIdx.x;
    int tx = tid & 15, ty = tid >> 4;
    int lr = tid >> 2, lk = (tid & 3) << 2;      // 64 rows x 16 k staging
    const float* Ap = A  + (size_t)(s0 + lr) * COUT + lk;
    const float* Bp = Bm + (size_t)(t0 + lr) * COUT + lk;
    float4 a0 = *(const float4*)(Ap);
    float4 b0 = *(const float4*)(Bp);
    float acc[4][4] = {};
    for (int kp = 0; kp < 16; kp++) {
        __syncthreads();
        As[lk + 0][lr] = a0.x; As[lk + 1][lr] = a0.y;
        As[lk + 2][lr] = a0.z; As[lk + 3][lr] = a0.w;
        Bs[lk + 0][lr] = b0.x; Bs[lk + 1][lr] = b0.y;
        Bs[lk + 2][lr] = b0.z; Bs[lk + 3][lr] = b0.w;
        __syncthreads();
        if (kp < 15) {
            a0 = *(const float4*)(Ap + (kp + 1) * 16);
            b0 = *(const float4*)(Bp + (kp + 1) * 16);
        }
#pragma unroll
        for (int k = 0; k < 16; k++) {
            float av[4], bv[4];
            *(float4*)&av[0] = *(const float4*)&As[k][ty * 4];
            *(float4*)&bv[0] = *(const float4*)&Bs[k][tx * 4];
#pragma unroll
            for (int i = 0; i < 4; i++)
#pragma unroll
                for (int j = 0; j < 4; j++)
                    acc[i][j] = fmaf(av[i], bv[j], acc[i][j]);
        }
    }
#pragma unroll
    for (int i = 0; i < 4; i++) {
        float4 v = make_float4(acc[i][0], acc[i][1], acc[i][2], acc[i][3]);
        *(float4*)(Sh + ((size_t)b * NSEQ + s0 + ty * 4 + i) * NSEQ + t0 + tx * 4) = v;
        float ml = fmaxf(fmaxf(v.x, v.y), fmaxf(v.z, v.w));
#pragma unroll
        for (int o = 1; o < 16; o <<= 1) ml = fmaxf(ml, __shfl_xor(ml, o, 16));
        float sl = __expf(v.x - ml) + __expf(v.y - ml) + __expf(v.z - ml) + __expf(v.w - ml);
#pragma unroll
        for (int o = 1; o < 16; o <<= 1) sl += __shfl_xor(sl, o, 16);
        if (tx == 0) {
            int grow = b * NSEQ + s0 + ty * 4 + i;
            pmax[grow * NTILE + bx] = ml;
            psum[grow * NTILE + bx] = sl;
        }
    }
}

// Combine per-tile stats -> row stats. 16 blocks x 256 threads, 1 row/thread.
__global__ void stats_combine(const float* __restrict__ pmax, const float* __restrict__ psum,
                              float* __restrict__ mstat, float* __restrict__ istat) {
    int row = blockIdx.x * blockDim.x + threadIdx.x;
    float pm[NTILE];
    float m = -3.4e38f;
#pragma unroll
    for (int t = 0; t < NTILE; t++) { pm[t] = pmax[row * NTILE + t]; m = fmaxf(m, pm[t]); }
    float s = 0.f;
#pragma unroll
    for (int t = 0; t < NTILE; t++) s += psum[row * NTILE + t] * __expf(pm[t] - m);
    mstat[row] = m;
    istat[row] = 1.0f / s;
}

// Final: f = sum_i sw[i]*softmax(Sh_i) (all stats precomputed); out = softmax(f).
__global__ void softmax_final3(const float* __restrict__ Sh0, const float* __restrict__ Sh1,
                               const float* __restrict__ Sh2, const float* __restrict__ mst,
                               const float* __restrict__ ist, const float* __restrict__ sw,
                               float* __restrict__ out) {
    int row = blockIdx.x, tid = threadIdx.x;
    __shared__ float redm[4], reds[4];
    int wid = tid >> 6, lane = tid & 63;
    float4 v0 = *(const float4*)(Sh0 + (size_t)row * NSEQ + tid * 4);
    float4 v1 = *(const float4*)(Sh1 + (size_t)row * NSEQ + tid * 4);
    float4 v2 = *(const float4*)(Sh2 + (size_t)row * NSEQ + tid * 4);
    float m0 = mst[row],           w0 = sw[0] * ist[row];
    float m1 = mst[BNN + row],     w1 = sw[1] * ist[BNN + row];
    float m2 = mst[2 * BNN + row], w2 = sw[2] * ist[2 * BNN + row];
    float4 f;
    f.x = fmaf(w0, __expf(v0.x - m0), fmaf(w1, __expf(v1.x - m1), w2 * __expf(v2.x - m2)));
    f.y = fmaf(w0, __expf(v0.y - m0), fmaf(w1, __expf(v1.y - m1), w2 * __expf(v2.y - m2)));
    f.z = fmaf(w0, __expf(v0.z - m0), fmaf(w1, __expf(v1.z - m1), w2 * __expf(v2.z - m2)));
    f.w = fmaf(w0, __expf(v0.w - m0), fmaf(w1, __expf(v1.w - m1), w2 * __expf(v2.w - m2)));
    float mf = fmaxf(fmaxf(f.x, f.y), fmaxf(f.z, f.w));
#pragma unroll
    for (int o = 32; o; o >>= 1) mf = fmaxf(mf, __shfl_xor(mf, o));
    if (lane == 0) redm[wid] = mf;
    __syncthreads();
    mf = fmaxf(fmaxf(redm[0], redm[1]), fmaxf(redm[2], redm[3]));
    float4 ef;
    ef.x = __expf(f.x - mf); ef.y = __expf(f.y - mf);
    ef.z = __expf(f.z - mf); ef.w = __expf(f.w - mf);
    float sf = ef.x + ef.y + ef.z + ef.w;
#pragma unroll
    for (int o = 32; o; o >>= 1) sf += __shfl_xor(sf, o);
    if (lane == 0) reds[wid] = sf;
    __syncthreads();
    sf = reds[0] + reds[1] + reds[2] + reds[3];
    float inv = 1.0f / sf;
    float4 sv = make_float4(ef.x * inv, ef.y * inv, ef.z * inv, ef.w * inv);
    *(float4*)(out + (size_t)row * NSEQ + tid * 4) = sv;
}

// rt partials from Sh + row stats.
__global__ void rt_part(const float* __restrict__ Sh, const float* __restrict__ mstat,
                        const float* __restrict__ istat, const float* __restrict__ rs,
                        float* __restrict__ part) {
    __shared__ float rsld[64][33];
    __shared__ float ml[64], il[64];
    int b = blockIdx.z, t0 = blockIdx.y * 128, s0 = blockIdx.x * 64;
    int tid = threadIdx.x;
    if (tid < 64) ml[tid] = mstat[b * NSEQ + s0 + tid];
    else if (tid < 128) il[tid - 64] = istat[b * NSEQ + s0 + tid - 64];
#pragma unroll
    for (int q = 0; q < 2; q++) {
        int lid = (tid << 1) + q;
        int srow = lid >> 3, c4 = (lid & 7) << 2;
        float4 v = *(const float4*)(rs + ((size_t)b * NSEQ + s0 + srow) * RDIM + c4);
        rsld[srow][c4] = v.x; rsld[srow][c4 + 1] = v.y;
        rsld[srow][c4 + 2] = v.z; rsld[srow][c4 + 3] = v.w;
    }
    __syncthreads();
    int t = t0 + (tid & 127);
    int j0 = (tid >> 7) << 4;
    float acc[16] = {};
    const float* Sp = Sh + ((size_t)b * NSEQ + s0) * NSEQ + t;
#pragma unroll 8
    for (int s = 0; s < 64; s++) {
        float p = __expf(Sp[(size_t)s * NSEQ] - ml[s]) * il[s];
#pragma unroll
        for (int j = 0; j < 16; j++) acc[j] = fmaf(p, rsld[s][j0 + j], acc[j]);
    }
    float* pp = part + (((size_t)blockIdx.x * NBATCH + b) * NSEQ + t) * RDIM + j0;
#pragma unroll
    for (int j4 = 0; j4 < 16; j4 += 4)
        *(float4*)(pp + j4) = make_float4(acc[j4], acc[j4 + 1], acc[j4 + 2], acc[j4 + 3]);
}

// rt[i4] = sum over 16 chunks of part[c][i4].
__global__ void rt_reduce(const float* __restrict__ part, float* __restrict__ rt) {
    int i = blockIdx.x * blockDim.x + threadIdx.x;   // 32768 float4
    const float4* p = (const float4*)part + i;
    float4 a = make_float4(0.f, 0.f, 0.f, 0.f);
#pragma unroll
    for (int c = 0; c < 16; c++) {
        float4 v = p[(size_t)c * (BNN * RDIM / 4)];
        a.x += v.x; a.y += v.y; a.z += v.z; a.w += v.w;
    }
    ((float4*)rt)[i] = a;
}

// o = relu(t_r @ Wp + bp); P = o @ Wm1 (+ bm1 for s-side). Both sides via grid.y.
// Also writes A[row] = sum_j P[row][j]*Wm2[j] (for the relu-split identity in upd_add).
__global__ void psi_r(const float* __restrict__ trs, const float* __restrict__ trt,
                      const float* __restrict__ Wp, const float* __restrict__ bp,
                      const float* __restrict__ Wm1, const float* __restrict__ bm1,
                      const float* __restrict__ Wm2,
                      float* __restrict__ Ps, float* __restrict__ Pt,
                      float* __restrict__ Aps, float* __restrict__ Apt) {
    __shared__ float sWp[32 * 32], sWm1[32 * 32];
    __shared__ float srow[8][33], so[8][33];
    __shared__ float swm2[32];
    int which = blockIdx.y;
    const float* t_r = which ? trt : trs;
    float* P = which ? Pt : Ps;
    float* A = which ? Apt : Aps;
    int tid = threadIdx.x;
#pragma unroll
    for (int q = 0; q < 4; q++) {
        sWp[tid + q * 256]  = Wp[tid + q * 256];
        sWm1[tid + q * 256] = Wm1[tid + q * 256];
    }
    if (tid < 32) swm2[tid] = Wm2[tid];
    int g = tid >> 5, j = tid & 31;
    int row = blockIdx.x * 8 + g;
    srow[g][j] = t_r[(size_t)row * RDIM + j];
    __syncthreads();
    float acc = bp[j];
#pragma unroll
    for (int k = 0; k < 32; k++) acc = fmaf(srow[g][k], sWp[k * 32 + j], acc);
    float o = fmaxf(acc, 0.f);
    so[g][j] = o;
    __syncthreads();
    float acc2 = which ? 0.f : bm1[j];
#pragma unroll
    for (int k = 0; k < 32; k++) acc2 = fmaf(so[g][k], sWm1[k * 32 + j], acc2);
    P[(size_t)row * RDIM + j] = acc2;
    float v = acc2 * swm2[j];
#pragma unroll
    for (int o2 = 16; o2; o2 >>= 1) v += __shfl_xor(v, o2, 32);
    if (j == 0) A[row] = v;
}

// Shout = Shin + upd; upd = 0.5*(Aps[s] - Apt[t] + sum_k |ps-pt|*w) + bm2.
// Transposed [k][row] LDS, float4 reads. Epilogue: per-(row, t-tile) stats.
__global__ __launch_bounds__(256) void upd_add_stats(const float* __restrict__ Ps,
                                                     const float* __restrict__ Pt,
                                                     const float* __restrict__ Aps,
                                                     const float* __restrict__ Apt,
                                                     const float* __restrict__ Wm2,
                                                     const float* __restrict__ bm2p,
                                                     const float* __restrict__ Shin,
                                                     float* __restrict__ Shout,
                                                     float* __restrict__ pmax,
                                                     float* __restrict__ psum) {
    __shared__ float sPsT[32][68];   // [k][s-row]
    __shared__ float sPtT[32][68];   // [k][t-col]
    __shared__ float swm[32];
    __shared__ float sAs[64], sAt[64];
    int b = blockIdx.z, s0 = blockIdx.y * 64, t0 = blockIdx.x * 64;
    int tid = threadIdx.x;
    {
        int lr = tid >> 2, lk = (tid & 3) << 3;   // 64 rows x 32 k, 8 floats/thread each
        const float* p = Ps + ((size_t)b * NSEQ + s0 + lr) * RDIM + lk;
        float4 v0 = *(const float4*)p, v1 = *(const float4*)(p + 4);
        sPsT[lk + 0][lr] = v0.x; sPsT[lk + 1][lr] = v0.y;
        sPsT[lk + 2][lr] = v0.z; sPsT[lk + 3][lr] = v0.w;
        sPsT[lk + 4][lr] = v1.x; sPsT[lk + 5][lr] = v1.y;
        sPsT[lk + 6][lr] = v1.z; sPsT[lk + 7][lr] = v1.w;
        const float* q = Pt + ((size_t)b * NSEQ + t0 + lr) * RDIM + lk;
        float4 u0 = *(const float4*)q, u1 = *(const float4*)(q + 4);
        sPtT[lk + 0][lr] = u0.x; sPtT[lk + 1][lr] = u0.y;
        sPtT[lk + 2][lr] = u0.z; sPtT[lk + 3][lr] = u0.w;
        sPtT[lk + 4][lr] = u1.x; sPtT[lk + 5][lr] = u1.y;
        sPtT[lk + 6][lr] = u1.z; sPtT[lk + 7][lr] = u1.w;
    }
    if (tid < 32) swm[tid] = Wm2[tid];
    else if (tid < 96)  sAs[tid - 32] = Aps[b * NSEQ + s0 + tid - 32];
    else if (tid < 160) sAt[tid - 96] = Apt[b * NSEQ + t0 + tid - 96];
    __syncthreads();
    int tx = tid & 15, ty = tid >> 4;
    float acc[4][4] = {};
#pragma unroll 8
    for (int k = 0; k < 32; k++) {
        float w = swm[k];
        float ps[4], pt[4];
        *(float4*)&ps[0] = *(const float4*)&sPsT[k][ty * 4];
        *(float4*)&pt[0] = *(const float4*)&sPtT[k][tx * 4];
#pragma unroll
        for (int i = 0; i < 4; i++)
#pragma unroll
            for (int j = 0; j < 4; j++)
                acc[i][j] = fmaf(fabsf(ps[i] - pt[j]), w, acc[i][j]);
    }
    float bm2 = bm2p[0];
#pragma unroll
    for (int i = 0; i < 4; i++) {
        float as = sAs[ty * 4 + i];
        size_t base = ((size_t)b * NSEQ + s0 + ty * 4 + i) * NSEQ + t0 + tx * 4;
        float4 old = *(const float4*)(Shin + base);
        float4 f;
        f.x = old.x + 0.5f * (acc[i][0] + as - sAt[tx * 4 + 0]) + bm2;
        f.y = old.y + 0.5f * (acc[i][1] + as - sAt[tx * 4 + 1]) + bm2;
        f.z = old.z + 0.5f * (acc[i][2] + as - sAt[tx * 4 + 2]) + bm2;
        f.w = old.w + 0.5f * (acc[i][3] + as - sAt[tx * 4 + 3]) + bm2;
        *(float4*)(Shout + base) = f;
        float ml = fmaxf(fmaxf(f.x, f.y), fmaxf(f.z, f.w));
#pragma unroll
        for (int o = 1; o < 16; o <<= 1) ml = fmaxf(ml, __shfl_xor(ml, o, 16));
        float sl = __expf(f.x - ml) + __expf(f.y - ml) + __expf(f.z - ml) + __expf(f.w - ml);
#pragma unroll
        for (int o = 1; o < 16; o <<= 1) sl += __shfl_xor(sl, o, 16);
        if (tx == 0) {
            int grow = b * NSEQ + s0 + ty * 4 + i;
            pmax[grow * NTILE + blockIdx.x] = ml;
            psum[grow * NTILE + blockIdx.x] = sl;
        }
    }
}

extern "C" void kernel_launch(void* const* d_in, const int* in_sizes, int n_in,
                              void* d_out, int out_size, void* d_ws, size_t ws_size,
                              hipStream_t stream) {
    const float* x_s  = (const float*)d_in[0];
    const int*   ei_s = (const int*)  d_in[1];
    const float* x_t  = (const float*)d_in[2];
    const int*   ei_t = (const int*)  d_in[3];
    const float* r    = (const float*)d_in[4];
    const float* W1   = (const float*)d_in[5];
    const float* b1   = (const float*)d_in[6];
    const float* Wp   = (const float*)d_in[7];
    const float* bp   = (const float*)d_in[8];
    const float* Wm1  = (const float*)d_in[9];
    const float* bm1  = (const float*)d_in[10];
    const float* Wm2  = (const float*)d_in[11];
    const float* bm2  = (const float*)d_in[12];
    const float* sw   = (const float*)d_in[13];
    float* out = (float*)d_out;

    float* ws = (float*)d_ws;
    float* t_s  = ws;  ws += (size_t)BNN * CIN;
    float* t_t  = ws;  ws += (size_t)BNN * CIN;
    float* h_s  = ws;  ws += (size_t)BNN * COUT;   // reused as rt partials in loop
    float* h_t  = ws;  ws += (size_t)BNN * COUT;
    float* Sh0  = ws;  ws += (size_t)NBATCH * NSEQ * NSEQ;
    float* Sh1  = ws;  ws += (size_t)NBATCH * NSEQ * NSEQ;
    float* Sh2  = ws;  ws += (size_t)NBATCH * NSEQ * NSEQ;
    float* mstat = ws; ws += 3 * BNN;
    float* istat = ws; ws += 3 * BNN;
    float* pmax = ws;  ws += (size_t)BNN * NTILE;
    float* psum = ws;  ws += (size_t)BNN * NTILE;
    float* rt   = ws;  ws += (size_t)BNN * RDIM;
    float* trs  = ws;  ws += (size_t)BNN * RDIM;
    float* trt  = ws;  ws += (size_t)BNN * RDIM;
    float* Ps   = ws;  ws += (size_t)BNN * RDIM;
    float* Pt   = ws;  ws += (size_t)BNN * RDIM;
    float* Aps  = ws;  ws += BNN;
    float* Apt  = ws;  ws += BNN;
    int* icnt  = (int*)ws;
    int* ioffs = icnt  + 2 * BNN;
    int* icur  = ioffs + 2 * (BNN + 1);
    int* issrc = icur  + 2 * BNN;   // 2*NEDGE ints
    float* rtpart = h_s;            // 16*BNN*RDIM floats = 8 MB, dead after shat

    float* ShA[3] = {Sh0, Sh1, Sh2};

    // ---- bucket edges by dst (both lists) ----
    hipMemsetAsync(icnt, 0, 2 * BNN * sizeof(int), stream);
    edge_hist <<<512, 256, 0, stream>>>(ei_s, ei_t, icnt);
    edge_scan <<<2, 256, 0, stream>>>(icnt, ioffs, icur);
    edge_place<<<512, 256, 0, stream>>>(ei_s, ei_t, icur, issrc);

    // ---- psi_1 for both graphs ----
    gather_agg128<<<8192, 128, 0, stream>>>(x_s, x_t, ioffs, issrc, t_s, t_t);
    psi1_gemm<<<1024, 256, 0, stream>>>(t_s, t_t, W1, b1, h_s, h_t);
    shat_gemm<<<1024, 256, 0, stream>>>(h_s, h_t, Sh0, pmax, psum);
    stats_combine<<<16, 256, 0, stream>>>(pmax, psum, mstat, istat);

    for (int i = 0; i < 2; i++) {
        rt_part<<<dim3(16, 8, 4), 256, 0, stream>>>(ShA[i], mstat + i * BNN, istat + i * BNN,
                                                    r + (size_t)i * BNN * RDIM, rtpart);
        rt_reduce<<<128, 256, 0, stream>>>(rtpart, rt);
        gather_agg32<<<dim3(512, 2), 256, 0, stream>>>(r + (size_t)i * BNN * RDIM, rt,
                                                       ioffs, issrc, trs, trt);
        psi_r<<<dim3(512, 2), 256, 0, stream>>>(trs, trt, Wp + i * RDIM * RDIM,
                                                bp + i * RDIM, Wm1, bm1, Wm2,
                                                Ps, Pt, Aps, Apt);
        upd_add_stats<<<dim3(16, 16, 4), 256, 0, stream>>>(Ps, Pt, Aps, Apt, Wm2, bm2,
                                                           ShA[i], ShA[i + 1], pmax, psum);
        stats_combine<<<16, 256, 0, stream>>>(pmax, psum, mstat + (i + 1) * BNN,
                                              istat + (i + 1) * BNN);
    }
    softmax_final3<<<4096, 256, 0, stream>>>(Sh0, Sh1, Sh2, mstat, istat, sw, out);
}

// Round 11
// 202.209 us; speedup vs baseline: 1.0221x; 1.0221x over previous
//
#include <hip/hip_runtime.h>
#include <hip/hip_bf16.h>

#define NBATCH 4
#define NSEQ   1024
#define BNN    4096
#define CIN    128
#define COUT   256
#define RDIM   32
#define NEDGE  65536

// ---------- edge bucketing (counting sort by dst) ----------
__global__ void edge_hist(const int* __restrict__ ei_s, const int* __restrict__ ei_t,
                          int* __restrict__ cnt) {
    int gid = blockIdx.x * blockDim.x + threadIdx.x;   // 2*NEDGE
    int list = gid >> 16;
    int e = gid & (NEDGE - 1);
    const int* ei = list ? ei_t : ei_s;
    atomicAdd(&cnt[list * BNN + ei[NEDGE + e]], 1);
}

__global__ void edge_scan(const int* __restrict__ cnt, int* __restrict__ offs,
                          int* __restrict__ cursor) {
    __shared__ int sums[256];
    int list = blockIdx.x;
    int tid = threadIdx.x;
    int local[16];
    int s = 0;
#pragma unroll
    for (int k = 0; k < 16; k++) { local[k] = cnt[list * BNN + tid * 16 + k]; s += local[k]; }
    sums[tid] = s;
    __syncthreads();
    for (int off = 1; off < 256; off <<= 1) {
        int v = 0;
        if (tid >= off) v = sums[tid - off];
        __syncthreads();
        if (tid >= off) sums[tid] += v;
        __syncthreads();
    }
    int run = tid ? sums[tid - 1] : 0;
#pragma unroll
    for (int k = 0; k < 16; k++) {
        offs[list * (BNN + 1) + tid * 16 + k] = run;
        cursor[list * BNN + tid * 16 + k] = run;
        run += local[k];
    }
    if (tid == 255) offs[list * (BNN + 1) + BNN] = run;
}

__global__ void edge_place(const int* __restrict__ ei_s, const int* __restrict__ ei_t,
                           int* __restrict__ cursor, int* __restrict__ ssrc) {
    int gid = blockIdx.x * blockDim.x + threadIdx.x;   // 2*NEDGE
    int list = gid >> 16;
    int e = gid & (NEDGE - 1);
    const int* ei = list ? ei_t : ei_s;
    int dst = ei[NEDGE + e], src = ei[e];
    int p = atomicAdd(&cursor[list * BNN + dst], 1);
    ssrc[list * NEDGE + p] = src;
}

// t[n] = x[n] + sum_{e: dst=n} x[src_e] (128-wide). One block (128 thr) per node.
__global__ void gather_agg128(const float* __restrict__ x_s, const float* __restrict__ x_t,
                              const int* __restrict__ offs, const int* __restrict__ ssrc,
                              float* __restrict__ t_s, float* __restrict__ t_t) {
    __shared__ int sl[128];
    int node = blockIdx.x & (BNN - 1);
    int list = blockIdx.x >> 12;
    const float* x = list ? x_t : x_s;
    float* t = list ? t_t : t_s;
    int c = threadIdx.x;
    int beg = offs[list * (BNN + 1) + node], end = offs[list * (BNN + 1) + node + 1];
    float acc = x[(size_t)node * CIN + c];
    for (int base = beg; base < end; base += 128) {
        int cnt = min(128, end - base);
        __syncthreads();
        if (c < cnt) sl[c] = ssrc[list * NEDGE + base + c];
        __syncthreads();
        int e = 0;
        for (; e + 4 <= cnt; e += 4) {
            int n0 = sl[e], n1 = sl[e + 1], n2 = sl[e + 2], n3 = sl[e + 3];
            acc += x[(size_t)n0 * CIN + c] + x[(size_t)n1 * CIN + c]
                 + x[(size_t)n2 * CIN + c] + x[(size_t)n3 * CIN + c];
        }
        for (; e < cnt; e++) acc += x[(size_t)sl[e] * CIN + c];
    }
    t[(size_t)node * CIN + c] = acc;
}

// 32-wide gather; blockIdx.y selects (rs->trs, list-s) or (rt->trt, list-t).
__global__ void gather_agg32(const float* __restrict__ rs, const float* __restrict__ rtin,
                             const int* __restrict__ offs, const int* __restrict__ ssrc,
                             float* __restrict__ trs, float* __restrict__ trt) {
    int list = blockIdx.y;
    int node = blockIdx.x * 8 + (threadIdx.x >> 5);
    int c = threadIdx.x & 31;
    const float* in = list ? rtin : rs;
    float* outp = list ? trt : trs;
    int beg = offs[list * (BNN + 1) + node], end = offs[list * (BNN + 1) + node + 1];
    float acc = in[(size_t)node * RDIM + c];
    for (int e = beg; e < end; e++)
        acc += in[(size_t)ssrc[list * NEDGE + e] * RDIM + c];
    outp[(size_t)node * RDIM + c] = acc;
}

// h = relu(t @ W1 + b1), both graphs in one launch (grid 1024).
__global__ void psi1_gemm(const float* __restrict__ t_s, const float* __restrict__ t_t,
                          const float* __restrict__ W1, const float* __restrict__ b1,
                          float* __restrict__ h_s, float* __restrict__ h_t) {
    __shared__ float rows[8][CIN];
    int half = blockIdx.x >> 9;
    const float* t = half ? t_t : t_s;
    float* h = half ? h_t : h_s;
    int r0 = (blockIdx.x & 511) * 8;
    int tid = threadIdx.x;
    {
        int rr = tid >> 5, c4 = (tid & 31) << 2;
        *(float4*)&rows[rr][c4] = *(const float4*)(t + (size_t)(r0 + rr) * CIN + c4);
    }
    __syncthreads();
    float acc[8];
    float bias = b1[tid];
#pragma unroll
    for (int r = 0; r < 8; r++) acc[r] = bias;
    for (int k = 0; k < CIN; k++) {
        float w = W1[k * COUT + tid];
#pragma unroll
        for (int r = 0; r < 8; r++) acc[r] = fmaf(rows[r][k], w, acc[r]);
    }
#pragma unroll
    for (int r = 0; r < 8; r++)
        h[(size_t)(r0 + r) * COUT + tid] = fmaxf(acc[r], 0.f);
}

// S_hat[b] = h_s[b] @ h_t[b]^T. 128(s)x64(t) tile, acc[8][4]. 1D grid 512 + XCD swizzle.
__global__ __launch_bounds__(256) void shat_gemm(const float* __restrict__ hs,
                                                 const float* __restrict__ ht,
                                                 float* __restrict__ Sh) {
    __shared__ float As[16][132];
    __shared__ float Bs[16][68];
    int flat = blockIdx.x;
    int swz = (flat & 7) * 64 + (flat >> 3);     // bijective: 512 % 8 == 0
    int bx = swz & 15, by = (swz >> 4) & 7, bz = swz >> 7;
    int b  = bz;
    int s0 = by * 128, t0 = bx * 64;
    const float* A  = hs + (size_t)b * NSEQ * COUT;
    const float* Bm = ht + (size_t)b * NSEQ * COUT;
    int tid = threadIdx.x;
    int tx = tid & 15, ty = tid >> 4;   // tx -> 4 t-cols, ty -> 8 s-rows
    int lrA = tid >> 1,  lkA = (tid & 1) * 8;   // A stage: 128 rows x 16 k
    int lrB = tid >> 2,  lkB = (tid & 3) * 4;   // B stage:  64 rows x 16 k
    const float* Ap = A  + (size_t)(s0 + lrA) * COUT + lkA;
    const float* Bp = Bm + (size_t)(t0 + lrB) * COUT + lkB;
    float4 a0 = *(const float4*)(Ap);
    float4 a1 = *(const float4*)(Ap + 4);
    float4 b0 = *(const float4*)(Bp);
    float acc[8][4] = {};
    for (int kp = 0; kp < 16; kp++) {
        __syncthreads();
        As[lkA + 0][lrA] = a0.x; As[lkA + 1][lrA] = a0.y;
        As[lkA + 2][lrA] = a0.z; As[lkA + 3][lrA] = a0.w;
        As[lkA + 4][lrA] = a1.x; As[lkA + 5][lrA] = a1.y;
        As[lkA + 6][lrA] = a1.z; As[lkA + 7][lrA] = a1.w;
        Bs[lkB + 0][lrB] = b0.x; Bs[lkB + 1][lrB] = b0.y;
        Bs[lkB + 2][lrB] = b0.z; Bs[lkB + 3][lrB] = b0.w;
        __syncthreads();
        if (kp < 15) {
            a0 = *(const float4*)(Ap + (kp + 1) * 16);
            a1 = *(const float4*)(Ap + (kp + 1) * 16 + 4);
            b0 = *(const float4*)(Bp + (kp + 1) * 16);
        }
#pragma unroll
        for (int k = 0; k < 16; k++) {
            float av[8], bv[4];
            *(float4*)&av[0] = *(const float4*)&As[k][ty * 8];
            *(float4*)&av[4] = *(const float4*)&As[k][ty * 8 + 4];
            *(float4*)&bv[0] = *(const float4*)&Bs[k][tx * 4];
#pragma unroll
            for (int i = 0; i < 8; i++)
#pragma unroll
                for (int j = 0; j < 4; j++)
                    acc[i][j] = fmaf(av[i], bv[j], acc[i][j]);
        }
    }
#pragma unroll
    for (int i = 0; i < 8; i++) {
        float4 v = make_float4(acc[i][0], acc[i][1], acc[i][2], acc[i][3]);
        *(float4*)(Sh + ((size_t)b * NSEQ + s0 + ty * 8 + i) * NSEQ + t0 + tx * 4) = v;
    }
}

// Row softmax stats of Sh: mstat[row]=max, istat[row]=1/sum. One block per row.
__global__ void softmax_stats(const float* __restrict__ Sh, float* __restrict__ mstat,
                              float* __restrict__ istat) {
    int row = blockIdx.x, tid = threadIdx.x;
    float4 v = *(const float4*)(Sh + (size_t)row * NSEQ + tid * 4);
    float m = fmaxf(fmaxf(v.x, v.y), fmaxf(v.z, v.w));
#pragma unroll
    for (int o = 32; o; o >>= 1) m = fmaxf(m, __shfl_xor(m, o));
    __shared__ float redm[4], reds[4];
    int wid = tid >> 6, lane = tid & 63;
    if (lane == 0) redm[wid] = m;
    __syncthreads();
    m = fmaxf(fmaxf(redm[0], redm[1]), fmaxf(redm[2], redm[3]));
    float s = __expf(v.x - m) + __expf(v.y - m) + __expf(v.z - m) + __expf(v.w - m);
#pragma unroll
    for (int o = 32; o; o >>= 1) s += __shfl_xor(s, o);
    if (lane == 0) reds[wid] = s;
    __syncthreads();
    if (tid == 0) {
        float tot = reds[0] + reds[1] + reds[2] + reds[3];
        mstat[row] = m;
        istat[row] = 1.0f / tot;
    }
}

// Final: f = sum_i sw[i]*softmax(Sh_i); out = softmax(f). One block per row.
__global__ void softmax_final3(const float* __restrict__ Sh0, const float* __restrict__ Sh1,
                               const float* __restrict__ Sh2, const float* __restrict__ m0a,
                               const float* __restrict__ i0a, const float* __restrict__ m1a,
                               const float* __restrict__ i1a, const float* __restrict__ sw,
                               float* __restrict__ out) {
    int row = blockIdx.x, tid = threadIdx.x;
    __shared__ float red[4];
    int wid = tid >> 6, lane = tid & 63;
    float4 v0 = *(const float4*)(Sh0 + (size_t)row * NSEQ + tid * 4);
    float4 v1 = *(const float4*)(Sh1 + (size_t)row * NSEQ + tid * 4);
    float4 v2 = *(const float4*)(Sh2 + (size_t)row * NSEQ + tid * 4);
    // stats of Sh2 in-register
    float m2 = fmaxf(fmaxf(v2.x, v2.y), fmaxf(v2.z, v2.w));
#pragma unroll
    for (int o = 32; o; o >>= 1) m2 = fmaxf(m2, __shfl_xor(m2, o));
    if (lane == 0) red[wid] = m2;
    __syncthreads();
    m2 = fmaxf(fmaxf(red[0], red[1]), fmaxf(red[2], red[3]));
    __syncthreads();
    float4 e2;
    e2.x = __expf(v2.x - m2); e2.y = __expf(v2.y - m2);
    e2.z = __expf(v2.z - m2); e2.w = __expf(v2.w - m2);
    float s2 = e2.x + e2.y + e2.z + e2.w;
#pragma unroll
    for (int o = 32; o; o >>= 1) s2 += __shfl_xor(s2, o);
    if (lane == 0) red[wid] = s2;
    __syncthreads();
    s2 = red[0] + red[1] + red[2] + red[3];
    __syncthreads();
    float w0 = sw[0] * i0a[row], w1 = sw[1] * i1a[row], w2 = sw[2] / s2;
    float m0 = m0a[row], m1 = m1a[row];
    float4 f;
    f.x = fmaf(w0, __expf(v0.x - m0), fmaf(w1, __expf(v1.x - m1), w2 * e2.x));
    f.y = fmaf(w0, __expf(v0.y - m0), fmaf(w1, __expf(v1.y - m1), w2 * e2.y));
    f.z = fmaf(w0, __expf(v0.z - m0), fmaf(w1, __expf(v1.z - m1), w2 * e2.z));
    f.w = fmaf(w0, __expf(v0.w - m0), fmaf(w1, __expf(v1.w - m1), w2 * e2.w));
    // softmax over f
    float mf = fmaxf(fmaxf(f.x, f.y), fmaxf(f.z, f.w));
#pragma unroll
    for (int o = 32; o; o >>= 1) mf = fmaxf(mf, __shfl_xor(mf, o));
    if (lane == 0) red[wid] = mf;
    __syncthreads();
    mf = fmaxf(fmaxf(red[0], red[1]), fmaxf(red[2], red[3]));
    __syncthreads();
    float4 ef;
    ef.x = __expf(f.x - mf); ef.y = __expf(f.y - mf);
    ef.z = __expf(f.z - mf); ef.w = __expf(f.w - mf);
    float sf = ef.x + ef.y + ef.z + ef.w;
#pragma unroll
    for (int o = 32; o; o >>= 1) sf += __shfl_xor(sf, o);
    if (lane == 0) red[wid] = sf;
    __syncthreads();
    sf = red[0] + red[1] + red[2] + red[3];
    float inv = 1.0f / sf;
    float4 sv = make_float4(ef.x * inv, ef.y * inv, ef.z * inv, ef.w * inv);
    *(float4*)(out + (size_t)row * NSEQ + tid * 4) = sv;
}

// rt partials from Sh + row stats.
__global__ void rt_part(const float* __restrict__ Sh, const float* __restrict__ mstat,
                        const float* __restrict__ istat, const float* __restrict__ rs,
                        float* __restrict__ part) {
    __shared__ float rsld[64][33];
    __shared__ float ml[64], il[64];
    int b = blockIdx.z, t0 = blockIdx.y * 128, s0 = blockIdx.x * 64;
    int tid = threadIdx.x;
    if (tid < 64) ml[tid] = mstat[b * NSEQ + s0 + tid];
    else if (tid < 128) il[tid - 64] = istat[b * NSEQ + s0 + tid - 64];
#pragma unroll
    for (int q = 0; q < 2; q++) {
        int lid = (tid << 1) + q;
        int srow = lid >> 3, c4 = (lid & 7) << 2;
        float4 v = *(const float4*)(rs + ((size_t)b * NSEQ + s0 + srow) * RDIM + c4);
        rsld[srow][c4] = v.x; rsld[srow][c4 + 1] = v.y;
        rsld[srow][c4 + 2] = v.z; rsld[srow][c4 + 3] = v.w;
    }
    __syncthreads();
    int t = t0 + (tid & 127);
    int j0 = (tid >> 7) << 4;
    float acc[16] = {};
    const float* Sp = Sh + ((size_t)b * NSEQ + s0) * NSEQ + t;
#pragma unroll 8
    for (int s = 0; s < 64; s++) {
        float p = __expf(Sp[(size_t)s * NSEQ] - ml[s]) * il[s];
#pragma unroll
        for (int j = 0; j < 16; j++) acc[j] = fmaf(p, rsld[s][j0 + j], acc[j]);
    }
    float* pp = part + (((size_t)blockIdx.x * NBATCH + b) * NSEQ + t) * RDIM + j0;
#pragma unroll
    for (int j4 = 0; j4 < 16; j4 += 4)
        *(float4*)(pp + j4) = make_float4(acc[j4], acc[j4 + 1], acc[j4 + 2], acc[j4 + 3]);
}

// rt[i4] = sum over 16 chunks of part[c][i4].
__global__ void rt_reduce(const float* __restrict__ part, float* __restrict__ rt) {
    int i = blockIdx.x * blockDim.x + threadIdx.x;   // 32768 float4
    const float4* p = (const float4*)part + i;
    float4 a = make_float4(0.f, 0.f, 0.f, 0.f);
#pragma unroll
    for (int c = 0; c < 16; c++) {
        float4 v = p[(size_t)c * (BNN * RDIM / 4)];
        a.x += v.x; a.y += v.y; a.z += v.z; a.w += v.w;
    }
    ((float4*)rt)[i] = a;
}

// o = relu(t_r @ Wp + bp); P = o @ Wm1 (+ bm1 for s-side). Both sides via grid.y.
// Also writes A[row] = sum_j P[row][j]*Wm2[j] (for the relu-split identity in upd_add).
__global__ void psi_r(const float* __restrict__ trs, const float* __restrict__ trt,
                      const float* __restrict__ Wp, const float* __restrict__ bp,
                      const float* __restrict__ Wm1, const float* __restrict__ bm1,
                      const float* __restrict__ Wm2,
                      float* __restrict__ Ps, float* __restrict__ Pt,
                      float* __restrict__ Aps, float* __restrict__ Apt) {
    __shared__ float sWp[32 * 32], sWm1[32 * 32];
    __shared__ float srow[8][33], so[8][33];
    __shared__ float swm2[32];
    int which = blockIdx.y;
    const float* t_r = which ? trt : trs;
    float* P = which ? Pt : Ps;
    float* A = which ? Apt : Aps;
    int tid = threadIdx.x;
#pragma unroll
    for (int q = 0; q < 4; q++) {
        sWp[tid + q * 256]  = Wp[tid + q * 256];
        sWm1[tid + q * 256] = Wm1[tid + q * 256];
    }
    if (tid < 32) swm2[tid] = Wm2[tid];
    int g = tid >> 5, j = tid & 31;
    int row = blockIdx.x * 8 + g;
    srow[g][j] = t_r[(size_t)row * RDIM + j];
    __syncthreads();
    float acc = bp[j];
#pragma unroll
    for (int k = 0; k < 32; k++) acc = fmaf(srow[g][k], sWp[k * 32 + j], acc);
    float o = fmaxf(acc, 0.f);
    so[g][j] = o;
    __syncthreads();
    float acc2 = which ? 0.f : bm1[j];
#pragma unroll
    for (int k = 0; k < 32; k++) acc2 = fmaf(so[g][k], sWm1[k * 32 + j], acc2);
    P[(size_t)row * RDIM + j] = acc2;
    float v = acc2 * swm2[j];
#pragma unroll
    for (int o2 = 16; o2; o2 >>= 1) v += __shfl_xor(v, o2, 32);
    if (j == 0) A[row] = v;
}

// Shout = Shin + upd; upd = 0.5*(Aps[s] - Apt[t] + sum_k |ps-pt|*w) + bm2.
// (relu(d)*w = 0.5*(d*w + |d|*w), exact.) 64x64 tile, transposed [k][row] LDS,
// float4 conflict-free reads, 2 VALU/k inner loop. Grid 1024 (4 blk/CU).
__global__ __launch_bounds__(256) void upd_add(const float* __restrict__ Ps,
                                               const float* __restrict__ Pt,
                                               const float* __restrict__ Aps,
                                               const float* __restrict__ Apt,
                                               const float* __restrict__ Wm2,
                                               const float* __restrict__ bm2p,
                                               const float* __restrict__ Shin,
                                               float* __restrict__ Shout) {
    __shared__ float sPsT[32][68];   // [k][s-row]
    __shared__ float sPtT[32][68];   // [k][t-col]
    __shared__ float swm[32];
    __shared__ float sAs[64], sAt[64];
    int b = blockIdx.z, s0 = blockIdx.y * 64, t0 = blockIdx.x * 64;
    int tid = threadIdx.x;
    {
        int lr = tid >> 2, lk = (tid & 3) << 3;   // 64 rows x 32 k, 8 floats/thread each
        const float* p = Ps + ((size_t)b * NSEQ + s0 + lr) * RDIM + lk;
        float4 v0 = *(const float4*)p, v1 = *(const float4*)(p + 4);
        sPsT[lk + 0][lr] = v0.x; sPsT[lk + 1][lr] = v0.y;
        sPsT[lk + 2][lr] = v0.z; sPsT[lk + 3][lr] = v0.w;
        sPsT[lk + 4][lr] = v1.x; sPsT[lk + 5][lr] = v1.y;
        sPsT[lk + 6][lr] = v1.z; sPsT[lk + 7][lr] = v1.w;
        const float* q = Pt + ((size_t)b * NSEQ + t0 + lr) * RDIM + lk;
        float4 u0 = *(const float4*)q, u1 = *(const float4*)(q + 4);
        sPtT[lk + 0][lr] = u0.x; sPtT[lk + 1][lr] = u0.y;
        sPtT[lk + 2][lr] = u0.z; sPtT[lk + 3][lr] = u0.w;
        sPtT[lk + 4][lr] = u1.x; sPtT[lk + 5][lr] = u1.y;
        sPtT[lk + 6][lr] = u1.z; sPtT[lk + 7][lr] = u1.w;
    }
    if (tid < 32) swm[tid] = Wm2[tid];
    else if (tid < 96)  sAs[tid - 32] = Aps[b * NSEQ + s0 + tid - 32];
    else if (tid < 160) sAt[tid - 96] = Apt[b * NSEQ + t0 + tid - 96];
    __syncthreads();
    int tx = tid & 15, ty = tid >> 4;
    float acc[4][4] = {};
#pragma unroll 8
    for (int k = 0; k < 32; k++) {
        float w = swm[k];
        float ps[4], pt[4];
        *(float4*)&ps[0] = *(const float4*)&sPsT[k][ty * 4];
        *(float4*)&pt[0] = *(const float4*)&sPtT[k][tx * 4];
#pragma unroll
        for (int i = 0; i < 4; i++)
#pragma unroll
            for (int j = 0; j < 4; j++)
                acc[i][j] = fmaf(fabsf(ps[i] - pt[j]), w, acc[i][j]);
    }
    float bm2 = bm2p[0];
#pragma unroll
    for (int i = 0; i < 4; i++) {
        float as = sAs[ty * 4 + i];
        size_t base = ((size_t)b * NSEQ + s0 + ty * 4 + i) * NSEQ + t0 + tx * 4;
        float4 old = *(const float4*)(Shin + base);
        float4 f;
        f.x = old.x + 0.5f * (acc[i][0] + as - sAt[tx * 4 + 0]) + bm2;
        f.y = old.y + 0.5f * (acc[i][1] + as - sAt[tx * 4 + 1]) + bm2;
        f.z = old.z + 0.5f * (acc[i][2] + as - sAt[tx * 4 + 2]) + bm2;
        f.w = old.w + 0.5f * (acc[i][3] + as - sAt[tx * 4 + 3]) + bm2;
        *(float4*)(Shout + base) = f;
    }
}

extern "C" void kernel_launch(void* const* d_in, const int* in_sizes, int n_in,
                              void* d_out, int out_size, void* d_ws, size_t ws_size,
                              hipStream_t stream) {
    const float* x_s  = (const float*)d_in[0];
    const int*   ei_s = (const int*)  d_in[1];
    const float* x_t  = (const float*)d_in[2];
    const int*   ei_t = (const int*)  d_in[3];
    const float* r    = (const float*)d_in[4];
    const float* W1   = (const float*)d_in[5];
    const float* b1   = (const float*)d_in[6];
    const float* Wp   = (const float*)d_in[7];
    const float* bp   = (const float*)d_in[8];
    const float* Wm1  = (const float*)d_in[9];
    const float* bm1  = (const float*)d_in[10];
    const float* Wm2  = (const float*)d_in[11];
    const float* bm2  = (const float*)d_in[12];
    const float* sw   = (const float*)d_in[13];
    float* out = (float*)d_out;

    float* ws = (float*)d_ws;
    float* t_s  = ws;  ws += (size_t)BNN * CIN;
    float* t_t  = ws;  ws += (size_t)BNN * CIN;
    float* h_s  = ws;  ws += (size_t)BNN * COUT;   // reused as rt partials in loop
    float* h_t  = ws;  ws += (size_t)BNN * COUT;
    float* Sh0  = ws;  ws += (size_t)NBATCH * NSEQ * NSEQ;
    float* Sh1  = ws;  ws += (size_t)NBATCH * NSEQ * NSEQ;
    float* Sh2  = ws;  ws += (size_t)NBATCH * NSEQ * NSEQ;
    float* mstat = ws; ws += 2 * BNN;
    float* istat = ws; ws += 2 * BNN;
    float* rt   = ws;  ws += (size_t)BNN * RDIM;
    float* trs  = ws;  ws += (size_t)BNN * RDIM;
    float* trt  = ws;  ws += (size_t)BNN * RDIM;
    float* Ps   = ws;  ws += (size_t)BNN * RDIM;
    float* Pt   = ws;  ws += (size_t)BNN * RDIM;
    float* Aps  = ws;  ws += BNN;
    float* Apt  = ws;  ws += BNN;
    int* icnt  = (int*)ws;
    int* ioffs = icnt  + 2 * BNN;
    int* icur  = ioffs + 2 * (BNN + 1);
    int* issrc = icur  + 2 * BNN;   // 2*NEDGE ints
    float* rtpart = h_s;            // 16*BNN*RDIM floats = 8 MB, dead after shat

    float* ShA[3] = {Sh0, Sh1, Sh2};

    // ---- bucket edges by dst (both lists) ----
    hipMemsetAsync(icnt, 0, 2 * BNN * sizeof(int), stream);
    edge_hist <<<512, 256, 0, stream>>>(ei_s, ei_t, icnt);
    edge_scan <<<2, 256, 0, stream>>>(icnt, ioffs, icur);
    edge_place<<<512, 256, 0, stream>>>(ei_s, ei_t, icur, issrc);

    // ---- psi_1 for both graphs ----
    gather_agg128<<<8192, 128, 0, stream>>>(x_s, x_t, ioffs, issrc, t_s, t_t);
    psi1_gemm<<<1024, 256, 0, stream>>>(t_s, t_t, W1, b1, h_s, h_t);
    shat_gemm<<<512, 256, 0, stream>>>(h_s, h_t, Sh0);

    for (int i = 0; i < 2; i++) {
        softmax_stats<<<4096, 256, 0, stream>>>(ShA[i], mstat + i * BNN, istat + i * BNN);
        rt_part<<<dim3(16, 8, 4), 256, 0, stream>>>(ShA[i], mstat + i * BNN, istat + i * BNN,
                                                    r + (size_t)i * BNN * RDIM, rtpart);
        rt_reduce<<<128, 256, 0, stream>>>(rtpart, rt);
        gather_agg32<<<dim3(512, 2), 256, 0, stream>>>(r + (size_t)i * BNN * RDIM, rt,
                                                       ioffs, issrc, trs, trt);
        psi_r<<<dim3(512, 2), 256, 0, stream>>>(trs, trt, Wp + i * RDIM * RDIM,
                                                bp + i * RDIM, Wm1, bm1, Wm2,
                                                Ps, Pt, Aps, Apt);
        upd_add<<<dim3(16, 16, 4), 256, 0, stream>>>(Ps, Pt, Aps, Apt, Wm2, bm2,
                                                     ShA[i], ShA[i + 1]);
    }
    softmax_final3<<<4096, 256, 0, stream>>>(Sh0, Sh1, Sh2, mstat, istat,
                                             mstat + BNN, istat + BNN, sw, out);
}